// Round 1
// baseline (74037.006 us; speedup 1.0000x reference)
//
#include <hip/hip_runtime.h>
#include <hip/hip_cooperative_groups.h>
#include <math.h>

namespace cg = cooperative_groups;

static constexpr int T_SEQ = 1024;
static constexpr int NBATCH = 128;
static constexpr int DIN = 128;
static constexpr int HID = 256;
static constexpr int DOUT = 1000;
static constexpr int KPAD = 516;   // 512 + 4 pad: breaks 8-way LDS bank conflict to free 2-way

// Persistent cooperative kernel: runs both LSTM layers, layer2 pipelined one
// step behind layer1, one grid.sync() per timestep (1025 phases total).
// Block layout: 256 blocks = 2 layers x (2 batch-groups of 64 x 64 unit-groups of 4 units).
// Each block: 16 Z-columns (4 units x 4 gates), weights transposed in LDS (persistent),
// cell state in registers (persistent), h exchanged via global double buffers in ws.
__global__ __launch_bounds__(512)
void lstm_loop_kernel(const float* __restrict__ x,
                      const float* __restrict__ W1, const float* __restrict__ U1,
                      const float* __restrict__ b1,
                      const float* __restrict__ W2, const float* __restrict__ U2,
                      const float* __restrict__ b2,
                      float* __restrict__ ws)
{
    __shared__ float wT[16 * KPAD];    // [local col c][k], c = ul*4 + gate
    __shared__ float zex[64 * 20];     // [local batch][16 cols], row stride 20 (pad)
    __shared__ float biasS[16];

    const int tid = threadIdx.x;
    const int bid = blockIdx.x;
    const int layer = bid >> 7;        // 0: LSTM1, 1: LSTM2
    const int lb = bid & 127;
    const int bg = lb >> 6;            // batch group: batches [bg*64, bg*64+64)
    const int ug = lb & 63;            // unit group: units [ug*4, ug*4+4)

    float* h1b[2] = { ws,          ws + 32768 };
    float* h2b[2] = { ws + 65536,  ws + 98304 };

    cg::grid_group grid = cg::this_grid();

    // zero initial hidden-state buffers (ws is poisoned 0xAA every call)
    {
        int gid = bid * 512 + tid;
        if (gid < NBATCH * HID) { h1b[0][gid] = 0.f; h2b[0][gid] = 0.f; }
    }

    // preload this block's 16 weight columns, transposed, into LDS (one-time)
    const int K = (layer == 0) ? (DIN + HID) : (2 * HID);
    for (int c = 0; c < 16; ++c) {
        const int ulc = c >> 2, gc = c & 3;
        const int col = gc * HID + ug * 4 + ulc;      // global Z column (gate-major)
        const float* s0 = (layer == 0 ? W1 : W2) + col;
        const float* s1 = (layer == 0 ? U1 : U2) + col;
        const int len0 = (layer == 0) ? DIN : HID;
        for (int k = tid; k < K; k += 512) {
            float v = (k < len0) ? s0[(size_t)k * (4 * HID)]
                                 : s1[(size_t)(k - len0) * (4 * HID)];
            wT[c * KPAD + k] = v;
        }
    }
    if (tid < 16) {
        const int ulc = tid >> 2, gc = tid & 3;
        biasS[tid] = (layer == 0 ? b1 : b2)[gc * HID + ug * 4 + ulc];
    }

    // GEMM mapping: thread = (batch b_l in [0,64), col-pair cy in [0,8))
    const int cy  = tid & 7;
    const int b_l = tid >> 3;
    const int b_g = bg * 64 + b_l;
    const int c0  = cy * 2;
    const float* wp0 = &wT[c0 * KPAD];
    const float* wp1 = &wT[(c0 + 1) * KPAD];

    // elementwise mapping (threads 0..255): one (batch, unit) cell state each
    const int eb   = tid >> 2;
    const int eu   = tid & 3;
    const int eb_g = bg * 64 + eb;
    const int eu_g = ug * 4 + eu;
    float cst = 0.f;                   // persistent cell state

    grid.sync();
    __threadfence();

    for (int p = 0; p <= T_SEQ; ++p) {
        const bool active = (layer == 0) ? (p < T_SEQ) : (p >= 1);
        if (active) {
            const int s = (layer == 0) ? p : (p - 1);
            const float* segA; int lenA; const float* segB;
            if (layer == 0) {
                segA = x + ((size_t)b_g * T_SEQ + p) * DIN;   // x_t row
                lenA = DIN;
                segB = h1b[s & 1] + b_g * HID;                // h1_{s-1}
            } else {
                segA = h1b[p & 1] + b_g * HID;                // h1_s (layer-1 output)
                lenA = HID;
                segB = h2b[s & 1] + b_g * HID;                // h2_{s-1}
            }
            float acc0 = 0.f, acc1 = 0.f;
            {
                const float4* a4  = (const float4*)segA;
                const float4* w04 = (const float4*)wp0;
                const float4* w14 = (const float4*)wp1;
                const int n4 = lenA >> 2;
                #pragma unroll 8
                for (int k4 = 0; k4 < n4; ++k4) {
                    float4 a = a4[k4], u0 = w04[k4], u1 = w14[k4];
                    acc0 = fmaf(a.x, u0.x, acc0); acc0 = fmaf(a.y, u0.y, acc0);
                    acc0 = fmaf(a.z, u0.z, acc0); acc0 = fmaf(a.w, u0.w, acc0);
                    acc1 = fmaf(a.x, u1.x, acc1); acc1 = fmaf(a.y, u1.y, acc1);
                    acc1 = fmaf(a.z, u1.z, acc1); acc1 = fmaf(a.w, u1.w, acc1);
                }
            }
            {
                const float4* a4  = (const float4*)segB;
                const float4* w04 = (const float4*)(wp0 + lenA);
                const float4* w14 = (const float4*)(wp1 + lenA);
                #pragma unroll 8
                for (int k4 = 0; k4 < (HID >> 2); ++k4) {
                    float4 a = a4[k4], u0 = w04[k4], u1 = w14[k4];
                    acc0 = fmaf(a.x, u0.x, acc0); acc0 = fmaf(a.y, u0.y, acc0);
                    acc0 = fmaf(a.z, u0.z, acc0); acc0 = fmaf(a.w, u0.w, acc0);
                    acc1 = fmaf(a.x, u1.x, acc1); acc1 = fmaf(a.y, u1.y, acc1);
                    acc1 = fmaf(a.z, u1.z, acc1); acc1 = fmaf(a.w, u1.w, acc1);
                }
            }
            zex[b_l * 20 + c0]     = acc0;
            zex[b_l * 20 + c0 + 1] = acc1;
            __syncthreads();
            if (tid < 256) {
                const float* zp = &zex[eb * 20 + eu * 4];
                const float* bp = &biasS[eu * 4];
                float zi = zp[0] + bp[0];
                float zf = zp[1] + bp[1];
                float zg = zp[2] + bp[2];
                float zo = zp[3] + bp[3];
                float ig = 1.f / (1.f + expf(-zi));
                float fg = 1.f / (1.f + expf(-zf));
                float gg = fmaxf(zg, 0.f);                 // activation = relu
                float og = 1.f / (1.f + expf(-zo));
                cst = fg * cst + ig * gg;
                float hv = og * fmaxf(cst, 0.f);           // h = o * relu(c)
                float* hout = (layer == 0) ? h1b[(s + 1) & 1] : h2b[(s + 1) & 1];
                hout[(size_t)eb_g * HID + eu_g] = hv;
            }
        }
        grid.sync();
        __threadfence();   // reader-side acquire: invalidate L1 before next phase's h loads
    }
    // final h2 (step 1023) lives in h2b[0] = ws + 65536
}

// Dense + softmax: one block per batch row.
__global__ __launch_bounds__(256)
void dense_softmax_kernel(const float* __restrict__ h, const float* __restrict__ Wd,
                          const float* __restrict__ bd, float* __restrict__ out)
{
    __shared__ float hs[HID];
    __shared__ float red[256];
    const int b = blockIdx.x, tid = threadIdx.x;

    hs[tid] = h[b * HID + tid];
    __syncthreads();

    float a0 = 0.f, a1 = 0.f, a2 = 0.f, a3 = 0.f;
    const bool has3 = (tid < DOUT - 768);
    const int c3 = has3 ? (tid + 768) : 0;
    for (int k = 0; k < HID; ++k) {
        const float hk = hs[k];
        const float* wr = Wd + (size_t)k * DOUT;
        a0 = fmaf(hk, wr[tid],       a0);
        a1 = fmaf(hk, wr[tid + 256], a1);
        a2 = fmaf(hk, wr[tid + 512], a2);
        a3 = fmaf(hk, wr[c3],        a3);
    }
    a0 += bd[tid]; a1 += bd[tid + 256]; a2 += bd[tid + 512];
    if (has3) a3 += bd[tid + 768];

    float m = fmaxf(fmaxf(a0, a1), a2);
    if (has3) m = fmaxf(m, a3);
    red[tid] = m; __syncthreads();
    for (int s = 128; s > 0; s >>= 1) {
        if (tid < s) red[tid] = fmaxf(red[tid], red[tid + s]);
        __syncthreads();
    }
    const float M = red[0];
    __syncthreads();

    float e0 = expf(a0 - M), e1 = expf(a1 - M), e2 = expf(a2 - M);
    float e3 = has3 ? expf(a3 - M) : 0.f;
    red[tid] = e0 + e1 + e2 + e3; __syncthreads();
    for (int s = 128; s > 0; s >>= 1) {
        if (tid < s) red[tid] += red[tid + s];
        __syncthreads();
    }
    const float inv = 1.f / red[0];

    float* o = out + (size_t)b * DOUT;
    o[tid] = e0 * inv;
    o[tid + 256] = e1 * inv;
    o[tid + 512] = e2 * inv;
    if (has3) o[tid + 768] = e3 * inv;
}

extern "C" void kernel_launch(void* const* d_in, const int* in_sizes, int n_in,
                              void* d_out, int out_size, void* d_ws, size_t ws_size,
                              hipStream_t stream)
{
    const float* x  = (const float*)d_in[0];
    const float* W1 = (const float*)d_in[1];
    const float* U1 = (const float*)d_in[2];
    const float* b1 = (const float*)d_in[3];
    const float* W2 = (const float*)d_in[4];
    const float* U2 = (const float*)d_in[5];
    const float* b2 = (const float*)d_in[6];
    const float* Wd = (const float*)d_in[7];
    const float* bd = (const float*)d_in[8];
    float* out = (float*)d_out;
    float* ws  = (float*)d_ws;   // uses 4 * 32768 floats = 512 KB

    void* args[] = { (void*)&x, (void*)&W1, (void*)&U1, (void*)&b1,
                     (void*)&W2, (void*)&U2, (void*)&b2, (void*)&ws };
    hipLaunchCooperativeKernel((const void*)lstm_loop_kernel,
                               dim3(256), dim3(512), args, 0, stream);

    hipLaunchKernelGGL(dense_softmax_kernel, dim3(128), dim3(256), 0, stream,
                       ws + 65536, Wd, bd, out);
}

// Round 2
// 44209.463 us; speedup vs baseline: 1.6747x; 1.6747x over previous
//
#include <hip/hip_runtime.h>
#include <math.h>

static constexpr int T_SEQ = 1024;
static constexpr int DIN = 128;
static constexpr int HID = 256;
static constexpr int DOUT = 1000;
static constexpr int KPAD = 516;    // wT col stride (floats): 516%32=4 -> 2-way (free) b128 reads
static constexpr int HS1_STR = 260; // layer1 h tile stride: rows land 4 banks apart -> conflict-free b128
static constexpr int HS2_STR = 520; // layer2 h tile stride: rows 8 banks apart -> conflict-free b128
static constexpr int SLOT = 32768;  // floats per h buffer (128x256)
static constexpr size_t SMEM_BYTES = (16 * KPAD + 16640 + 64 * 20 + 16) * 4; // 104768

#define SCOPE_AGENT __HIP_MEMORY_SCOPE_AGENT

__device__ __forceinline__ int ld_flag(const int* p) {
    return __hip_atomic_load(p, __ATOMIC_RELAXED, SCOPE_AGENT);
}
__device__ __forceinline__ void st_flag(int* p, int v) {
    __hip_atomic_store(p, v, __ATOMIC_RELAXED, SCOPE_AGENT);
}
__device__ __forceinline__ float ld_coh(const float* p) {
    return __hip_atomic_load(p, __ATOMIC_RELAXED, SCOPE_AGENT);
}
__device__ __forceinline__ void st_coh(float* p, float v) {
    __hip_atomic_store(p, v, __ATOMIC_RELAXED, SCOPE_AGENT);
}

// spin until all 64 flags in fA >= tA and all in fB >= tB (lane l checks entry l)
__device__ __forceinline__ void poll2(const int* fA, int tA, const int* fB, int tB, int lane) {
    for (;;) {
        int a = ld_flag(fA + lane);
        int b = ld_flag(fB + lane);
        if (__all((a >= tA) && (b >= tB))) break;
        __builtin_amdgcn_s_sleep(1);
    }
    __builtin_amdgcn_fence(__ATOMIC_ACQUIRE, "agent"); // one cheap acquire per step
}

#define FMA8(a, u0, u1)                                                  \
    acc0 = fmaf(a.x, u0.x, acc0); acc0 = fmaf(a.y, u0.y, acc0);          \
    acc0 = fmaf(a.z, u0.z, acc0); acc0 = fmaf(a.w, u0.w, acc0);          \
    acc1 = fmaf(a.x, u1.x, acc1); acc1 = fmaf(a.y, u1.y, acc1);          \
    acc1 = fmaf(a.z, u1.z, acc1); acc1 = fmaf(a.w, u1.w, acc1);

// 256 blocks x 512 threads, 1 block/CU (105KB LDS). No grid.sync: point-to-point
// flag/dataflow sync via agent-scope (L2-bypass) atomics. Layer2 pipelined 1 step
// behind layer1. h1: ring of 3 slots (in d_out scratch). h2: 2 slots (in ws).
__global__ __launch_bounds__(512)
void lstm_pipe_kernel(const float* __restrict__ x,
                      const float* __restrict__ W1, const float* __restrict__ U1,
                      const float* __restrict__ b1,
                      const float* __restrict__ W2, const float* __restrict__ U2,
                      const float* __restrict__ b2,
                      float* __restrict__ h1ring,   // 3*SLOT floats (d_out scratch)
                      float* __restrict__ ws)       // [256 int flags][2*SLOT h2]
{
    extern __shared__ float smem[];
    float* wT    = smem;                    // 16 x KPAD
    float* hs    = smem + 16 * KPAD;        // 16640 floats: [64][260] or [32][520]
    float* zex   = hs + 16640;              // 64 x 20
    float* biasS = zex + 64 * 20;           // 16

    int* flags = (int*)ws;                  // fL1: [0..127], fL2: [128..255]
    float* h2b = ws + 256;                  // 2 slots x SLOT

    const int tid  = threadIdx.x;
    const int lane = tid & 63;
    const int bid  = blockIdx.x;
    const int layer = bid >> 7;
    const int lb = bid & 127;
    const int bg = lb >> 6;                 // batches [bg*64, bg*64+64)
    const int ug = lb & 63;                 // units   [ug*4, ug*4+4)

    int* grpF1 = flags + bg * 64;           // layer1 group flags (this bg)
    int* grpF2 = flags + 128 + bg * 64;     // layer2 group flags (this bg)
    int* myF   = (layer ? grpF2 : grpF1) + ug;

    // ---- one-time: weights transposed into LDS ----
    const int K    = layer ? 2 * HID : (DIN + HID);
    const int len0 = layer ? HID : DIN;
    const float* Wp = layer ? W2 : W1;
    const float* Up = layer ? U2 : U1;
    for (int c = 0; c < 16; ++c) {
        const int col = (c & 3) * HID + ug * 4 + (c >> 2);   // gate-major Z column
        for (int k = tid; k < K; k += 512) {
            float v = (k < len0) ? Wp[(size_t)k * (4 * HID) + col]
                                 : Up[(size_t)(k - len0) * (4 * HID) + col];
            wT[c * KPAD + k] = v;
        }
    }
    if (tid < 16) biasS[tid] = (layer ? b2 : b1)[(tid & 3) * HID + ug * 4 + (tid >> 2)];
    __syncthreads();

    if (layer == 0) {
        // ---------------- LAYER 1 ----------------
        const int cy  = tid & 7;            // col-pair 0..7
        const int b_l = tid >> 3;           // batch 0..63
        const int b_g = bg * 64 + b_l;
        const float* wp0 = wT + (2 * cy) * KPAD;
        const float* wp1 = wp0 + KPAD;
        const int eb = tid >> 2, eu = tid & 3;   // elementwise map (tid<256)
        float cst = 0.f;

        for (int s = 0; s < T_SEQ; ++s) {
            // need: own group done step s-1; layer2 done with h1[s-3] (ring gate)
            if (s > 0) poll2(grpF1, s, grpF2, s - 2, lane);

            // stage h1[s-1] (ring slot (s-1)mod3) -> hs[64][260]
            const float* hprev = h1ring + (size_t)((s + 2) % 3) * SLOT + (size_t)bg * 64 * HID;
            if (s == 0) {
                for (int i = tid; i < 64 * HID; i += 512)
                    hs[(i >> 8) * HS1_STR + (i & 255)] = 0.f;
            } else {
                for (int i = tid; i < 64 * HID; i += 512)
                    hs[(i >> 8) * HS1_STR + (i & 255)] = ld_coh(hprev + i);
            }
            __syncthreads();

            // GEMM: z[b_l][2cy..2cy+1] = [x_t ; h1prev] . wT
            float acc0 = 0.f, acc1 = 0.f;
            {
                const float4* a4  = (const float4*)(x + ((size_t)b_g * T_SEQ + s) * DIN);
                const float4* w04 = (const float4*)wp0;
                const float4* w14 = (const float4*)wp1;
                #pragma unroll 8
                for (int k4 = 0; k4 < DIN / 4; ++k4) {
                    float4 a = a4[k4], u0 = w04[k4], u1 = w14[k4];
                    FMA8(a, u0, u1)
                }
            }
            {
                const float4* h4  = (const float4*)(hs + b_l * HS1_STR);
                const float4* w04 = (const float4*)(wp0 + DIN);
                const float4* w14 = (const float4*)(wp1 + DIN);
                #pragma unroll 8
                for (int k4 = 0; k4 < HID / 4; ++k4) {
                    float4 a = h4[k4], u0 = w04[k4], u1 = w14[k4];
                    FMA8(a, u0, u1)
                }
            }
            zex[b_l * 20 + 2 * cy]     = acc0;
            zex[b_l * 20 + 2 * cy + 1] = acc1;
            __syncthreads();

            if (tid < 256) {   // waves 0-3: uniform branch
                const float* zp = zex + eb * 20 + eu * 4;
                const float* bp = biasS + eu * 4;
                float zi = zp[0] + bp[0], zf = zp[1] + bp[1];
                float zg = zp[2] + bp[2], zo = zp[3] + bp[3];
                float ig = 1.f / (1.f + expf(-zi));
                float fg = 1.f / (1.f + expf(-zf));
                float gg = fmaxf(zg, 0.f);
                float og = 1.f / (1.f + expf(-zo));
                cst = fg * cst + ig * gg;
                float hv = og * fmaxf(cst, 0.f);
                st_coh(h1ring + (size_t)(s % 3) * SLOT
                              + (size_t)(bg * 64 + eb) * HID + ug * 4 + eu, hv);
                __builtin_amdgcn_s_waitcnt(0);   // drain own write-through store
            }
            __syncthreads();
            if (tid == 0) st_flag(myF, s + 1);
        }
    } else {
        // ---------------- LAYER 2 ----------------
        const int cp  = tid & 15;           // col 0..15
        const int b_l = tid >> 4;           // batch-in-half 0..31
        const float* wpc = wT + cp * KPAD;
        const int eb = tid >> 2, eu = tid & 3;   // elementwise (tid<128): eb 0..31
        float cst[2] = {0.f, 0.f};

        for (int s = 0; s < T_SEQ; ++s) {
            // need: h1[s] ready (fL1 >= s+1); own group done s-1 (fL2 >= s)
            poll2(grpF1, s + 1, grpF2, s, lane);

            const float* h1s = h1ring + (size_t)(s % 3) * SLOT + (size_t)bg * 64 * HID;
            const float* h2s = h2b + (size_t)((s + 1) & 1) * SLOT + (size_t)bg * 64 * HID;
            float*       h2o = h2b + (size_t)(s & 1) * SLOT + (size_t)bg * 64 * HID;

            for (int hf = 0; hf < 2; ++hf) {   // two 32-batch halves
                const float* pa = h1s + hf * 32 * HID;
                const float* pb = h2s + hf * 32 * HID;
                for (int i = tid; i < 32 * 512; i += 512) {
                    const int r = i >> 9, k = i & 511;
                    float v;
                    if (k < 256) v = ld_coh(pa + r * HID + k);
                    else         v = (s == 0) ? 0.f : ld_coh(pb + r * HID + (k - 256));
                    hs[r * HS2_STR + k] = v;
                }
                __syncthreads();

                float acc = 0.f;
                {
                    const float4* h4 = (const float4*)(hs + b_l * HS2_STR);
                    const float4* w4 = (const float4*)wpc;
                    #pragma unroll 8
                    for (int k4 = 0; k4 < (2 * HID) / 4; ++k4) {
                        float4 a = h4[k4], w = w4[k4];
                        acc = fmaf(a.x, w.x, acc); acc = fmaf(a.y, w.y, acc);
                        acc = fmaf(a.z, w.z, acc); acc = fmaf(a.w, w.w, acc);
                    }
                }
                zex[b_l * 20 + cp] = acc;
                __syncthreads();

                if (tid < 128) {   // waves 0-1: uniform branch
                    const float* zp = zex + eb * 20 + eu * 4;
                    const float* bp = biasS + eu * 4;
                    float zi = zp[0] + bp[0], zf = zp[1] + bp[1];
                    float zg = zp[2] + bp[2], zo = zp[3] + bp[3];
                    float ig = 1.f / (1.f + expf(-zi));
                    float fg = 1.f / (1.f + expf(-zf));
                    float gg = fmaxf(zg, 0.f);
                    float og = 1.f / (1.f + expf(-zo));
                    cst[hf] = fg * cst[hf] + ig * gg;
                    float hv = og * fmaxf(cst[hf], 0.f);
                    st_coh(h2o + (size_t)(hf * 32 + eb) * HID + ug * 4 + eu, hv);
                    __builtin_amdgcn_s_waitcnt(0);
                }
                __syncthreads();
            }
            if (tid == 0) st_flag(myF, s + 1);
        }
    }
}

// Dense + softmax: one block per batch row.
__global__ __launch_bounds__(256)
void dense_softmax_kernel(const float* __restrict__ h, const float* __restrict__ Wd,
                          const float* __restrict__ bd, float* __restrict__ out)
{
    __shared__ float hsd[HID];
    __shared__ float red[256];
    const int b = blockIdx.x, tid = threadIdx.x;

    hsd[tid] = h[b * HID + tid];
    __syncthreads();

    float a0 = 0.f, a1 = 0.f, a2 = 0.f, a3 = 0.f;
    const bool has3 = (tid < DOUT - 768);
    const int c3 = has3 ? (tid + 768) : 0;
    for (int k = 0; k < HID; ++k) {
        const float hk = hsd[k];
        const float* wr = Wd + (size_t)k * DOUT;
        a0 = fmaf(hk, wr[tid],       a0);
        a1 = fmaf(hk, wr[tid + 256], a1);
        a2 = fmaf(hk, wr[tid + 512], a2);
        a3 = fmaf(hk, wr[c3],        a3);
    }
    a0 += bd[tid]; a1 += bd[tid + 256]; a2 += bd[tid + 512];
    if (has3) a3 += bd[tid + 768];

    float m = fmaxf(fmaxf(a0, a1), a2);
    if (has3) m = fmaxf(m, a3);
    red[tid] = m; __syncthreads();
    for (int s = 128; s > 0; s >>= 1) {
        if (tid < s) red[tid] = fmaxf(red[tid], red[tid + s]);
        __syncthreads();
    }
    const float M = red[0];
    __syncthreads();

    float e0 = expf(a0 - M), e1 = expf(a1 - M), e2 = expf(a2 - M);
    float e3 = has3 ? expf(a3 - M) : 0.f;
    red[tid] = e0 + e1 + e2 + e3; __syncthreads();
    for (int s = 128; s > 0; s >>= 1) {
        if (tid < s) red[tid] += red[tid + s];
        __syncthreads();
    }
    const float inv = 1.f / red[0];

    float* o = out + (size_t)b * DOUT;
    o[tid] = e0 * inv;
    o[tid + 256] = e1 * inv;
    o[tid + 512] = e2 * inv;
    if (has3) o[tid + 768] = e3 * inv;
}

extern "C" void kernel_launch(void* const* d_in, const int* in_sizes, int n_in,
                              void* d_out, int out_size, void* d_ws, size_t ws_size,
                              hipStream_t stream)
{
    const float* x  = (const float*)d_in[0];
    const float* W1 = (const float*)d_in[1];
    const float* U1 = (const float*)d_in[2];
    const float* b1 = (const float*)d_in[3];
    const float* W2 = (const float*)d_in[4];
    const float* U2 = (const float*)d_in[5];
    const float* b2 = (const float*)d_in[6];
    const float* Wd = (const float*)d_in[7];
    const float* bd = (const float*)d_in[8];
    float* out = (float*)d_out;
    float* ws  = (float*)d_ws;

    // h1 ring (3 x 128KB) lives in d_out scratch space (fully overwritten by
    // dense_softmax at the end; dense reads only from ws -> no RAW race).
    float* h1ring = out;

    // flags must start at 0 (ws is poisoned 0xAA). h buffers need no init:
    // step-0 staging substitutes zeros in-kernel.
    hipMemsetAsync(ws, 0, 256 * sizeof(int), stream);

    hipFuncSetAttribute((const void*)lstm_pipe_kernel,
                        hipFuncAttributeMaxDynamicSharedMemorySize, (int)SMEM_BYTES);

    void* args[] = { (void*)&x, (void*)&W1, (void*)&U1, (void*)&b1,
                     (void*)&W2, (void*)&U2, (void*)&b2,
                     (void*)&h1ring, (void*)&ws };
    hipLaunchCooperativeKernel((const void*)lstm_pipe_kernel,
                               dim3(256), dim3(512), args, (int)SMEM_BYTES, stream);

    // final h2 = slot (1023 & 1) = 1
    const float* h2final = ws + 256 + SLOT;
    hipLaunchKernelGGL(dense_softmax_kernel, dim3(128), dim3(256), 0, stream,
                       h2final, Wd, bd, out);
}

// Round 4
// 35199.576 us; speedup vs baseline: 2.1033x; 1.2560x over previous
//
#include <hip/hip_runtime.h>
#include <math.h>

static constexpr int T_SEQ = 1024;
static constexpr int DIN = 128;
static constexpr int HID = 256;
static constexpr int DOUT = 1000;
static constexpr int WSTR  = 516;   // wT col stride (floats), 16B-aligned rows, non-pow2 banks
static constexpr int H1STR = 388;   // L1 [x|h] tile row stride (384+4)
static constexpr int H2STR = 520;   // L2 [h1|h2] tile row stride (512+8)
static constexpr int SLOT  = 32768; // floats per h buffer (128x256)

// LDS floats: wT 16*516=8256 | hs 64*388=24832 | zex 1280 | hvs 256 | bias 16
static constexpr int OFF_HS  = 8256;
static constexpr int OFF_ZEX = OFF_HS + 24832;
static constexpr int OFF_HVS = OFF_ZEX + 1280;
static constexpr int OFF_BIA = OFF_HVS + 256;
static constexpr size_t SMEM_BYTES = (size_t)(OFF_BIA + 16) * sizeof(float); // 138,560 B

typedef float v4f __attribute__((ext_vector_type(4)));

#define SCOPE_AGENT __HIP_MEMORY_SCOPE_AGENT

__device__ __forceinline__ int ld_flag(const int* p) {
    return __hip_atomic_load(p, __ATOMIC_RELAXED, SCOPE_AGENT);
}
__device__ __forceinline__ void st_flag(int* p, int v) {
    __hip_atomic_store(p, v, __ATOMIC_RELAXED, SCOPE_AGENT);
}
// 16B write-through store to the coherence point (bypass L1+L2)
__device__ __forceinline__ void store_wt16(float* p, v4f v) {
    asm volatile("global_store_dwordx4 %0, %1, off sc0 sc1" :: "v"(p), "v"(v) : "memory");
}

// NOTE: was a macro DOT4(acc,a,w) in R3 — macro param `w` collided with the
// vector member token `.w` (preprocessor substitutes after `.`), so it's a
// function now.
__device__ __forceinline__ float dot4(float acc, v4f va, v4f vb) {
    return fmaf(va.x, vb.x, fmaf(va.y, vb.y,
           fmaf(va.z, vb.z, fmaf(va.w, vb.w, acc))));
}

// 256 blocks x 512 threads, 1 block/CU (138.5 KB LDS). Point-to-point dataflow
// sync: per-block flags (R2 semantics), polled by wave0 only; bulk h exchanged
// via cached loads + one acquire-fence(agent) (L1/L2 inv) per step; producers
// publish h with sc0sc1 write-through dwordx4 + waitcnt before flagging.
// GEMMs: 4x4 register blocking, K-split across waves, LDS atomicAdd reduction.
__global__ __launch_bounds__(512)
void lstm_pipe_kernel(const float* __restrict__ x,
                      const float* __restrict__ W1, const float* __restrict__ U1,
                      const float* __restrict__ b1,
                      const float* __restrict__ W2, const float* __restrict__ U2,
                      const float* __restrict__ b2,
                      float* __restrict__ h1ring,   // 3*SLOT floats (d_out scratch)
                      float* __restrict__ ws)       // [256 int flags][2*SLOT h2]
{
    extern __shared__ float smem[];
    float* wT    = smem;
    float* hs    = smem + OFF_HS;
    float* zex   = smem + OFF_ZEX;   // 64 x 20, holds full z sums via LDS atomics
    float* hvs   = smem + OFF_HVS;   // 64 x 4 staged h values for x4 stores
    float* biasS = smem + OFF_BIA;

    int* flags = (int*)ws;           // fL1: [0..127], fL2: [128..255]
    float* h2b = ws + 256;

    const int tid  = threadIdx.x;
    const int bid  = blockIdx.x;
    const int layer = bid >> 7;
    const int lb = bid & 127;
    const int bg = lb >> 6;          // batches [bg*64, bg*64+64)
    const int ug = lb & 63;          // units   [ug*4, ug*4+4)

    int* grpF1 = flags + bg * 64;
    int* grpF2 = flags + 128 + bg * 64;
    int* myF   = (layer ? grpF2 : grpF1) + ug;

    // ---- one-time: weights transposed into LDS; zex zeroed ----
    const int K    = layer ? 2 * HID : (DIN + HID);
    const int len0 = layer ? HID : DIN;
    const float* Wp = layer ? W2 : W1;
    const float* Up = layer ? U2 : U1;
    for (int c = 0; c < 16; ++c) {
        const int col = (c & 3) * HID + ug * 4 + (c >> 2);   // gate-major Z column
        for (int k = tid; k < K; k += 512) {
            float v = (k < len0) ? Wp[(size_t)k * (4 * HID) + col]
                                 : Up[(size_t)(k - len0) * (4 * HID) + col];
            wT[c * WSTR + k] = v;
        }
    }
    if (tid < 16) biasS[tid] = (layer ? b2 : b1)[(tid & 3) * HID + ug * 4 + (tid >> 2)];
    for (int i = tid; i < 1280; i += 512) zex[i] = 0.f;
    __syncthreads();

    if (layer == 0) {
        // ---------------- LAYER 1 ----------------
        const int ks = tid >> 6;             // k-split 0..7 (wave-uniform), K-seg = 48
        const int bq = (tid >> 2) & 15;      // batch-quad 0..15
        const int cq = tid & 3;              // col-quad 0..3
        const int kb4 = ks * 12;
        const int eb = tid >> 2, eu = tid & 3;   // ew map (tid<256)
        float cst = 0.f;

        for (int s = 0; s < T_SEQ; ++s) {
            // stage x_t -> hs[.][0..128)  (independent of h: overlaps the poll)
            #pragma unroll
            for (int j = 0; j < 4; ++j) {
                const int idx = tid + j * 512, r = idx >> 5, c4 = idx & 31;
                v4f v = *(const v4f*)(x + ((size_t)(bg * 64 + r) * T_SEQ + s) * DIN + c4 * 4);
                *(v4f*)(hs + r * H1STR + c4 * 4) = v;
            }
            // wave0: wait own group done s-1, L2 done s-3 (ring gate); then inv caches
            if (tid < 64) {
                const int ta = s, tb = s - 2;
                for (;;) {
                    int a = ld_flag(grpF1 + tid);
                    int b = ld_flag(grpF2 + tid);
                    if (__all((a >= ta) && (b >= tb))) break;
                    __builtin_amdgcn_s_sleep(2);
                }
                __builtin_amdgcn_fence(__ATOMIC_ACQUIRE, "agent");
            }
            __syncthreads();                                   // B1

            // stage h1[s-1] -> hs[.][128..384)  (cached loads, post-inv)
            const float* hp = h1ring + (size_t)((s + 2) % 3) * SLOT + (size_t)bg * 64 * HID;
            #pragma unroll
            for (int j = 0; j < 8; ++j) {
                const int idx = tid + j * 512, r = idx >> 6, c4 = idx & 63;
                v4f v;
                if (s == 0) { v4f z = {0.f, 0.f, 0.f, 0.f}; v = z; }
                else        v = *(const v4f*)(hp + r * HID + c4 * 4);
                *(v4f*)(hs + r * H1STR + 128 + c4 * 4) = v;
            }
            __syncthreads();                                   // B2

            // GEMM: 4 batches x 4 cols per thread over K-seg 48; reduce via LDS atomics
            {
                const v4f* A0 = (const v4f*)(hs + (bq * 4 + 0) * H1STR) + kb4;
                const v4f* A1 = (const v4f*)(hs + (bq * 4 + 1) * H1STR) + kb4;
                const v4f* A2 = (const v4f*)(hs + (bq * 4 + 2) * H1STR) + kb4;
                const v4f* A3 = (const v4f*)(hs + (bq * 4 + 3) * H1STR) + kb4;
                const v4f* W0 = (const v4f*)(wT + (cq * 4 + 0) * WSTR) + kb4;
                const v4f* W1v = (const v4f*)(wT + (cq * 4 + 1) * WSTR) + kb4;
                const v4f* W2v = (const v4f*)(wT + (cq * 4 + 2) * WSTR) + kb4;
                const v4f* W3v = (const v4f*)(wT + (cq * 4 + 3) * WSTR) + kb4;
                float acc[4][4] = {};
                #pragma unroll
                for (int j = 0; j < 12; ++j) {
                    v4f a0 = A0[j], a1 = A1[j], a2 = A2[j], a3 = A3[j];
                    v4f w0 = W0[j], w1 = W1v[j], w2 = W2v[j], w3 = W3v[j];
                    acc[0][0] = dot4(acc[0][0], a0, w0); acc[0][1] = dot4(acc[0][1], a0, w1);
                    acc[0][2] = dot4(acc[0][2], a0, w2); acc[0][3] = dot4(acc[0][3], a0, w3);
                    acc[1][0] = dot4(acc[1][0], a1, w0); acc[1][1] = dot4(acc[1][1], a1, w1);
                    acc[1][2] = dot4(acc[1][2], a1, w2); acc[1][3] = dot4(acc[1][3], a1, w3);
                    acc[2][0] = dot4(acc[2][0], a2, w0); acc[2][1] = dot4(acc[2][1], a2, w1);
                    acc[2][2] = dot4(acc[2][2], a2, w2); acc[2][3] = dot4(acc[2][3], a2, w3);
                    acc[3][0] = dot4(acc[3][0], a3, w0); acc[3][1] = dot4(acc[3][1], a3, w1);
                    acc[3][2] = dot4(acc[3][2], a3, w2); acc[3][3] = dot4(acc[3][3], a3, w3);
                }
                #pragma unroll
                for (int i = 0; i < 4; ++i)
                    #pragma unroll
                    for (int c = 0; c < 4; ++c)
                        atomicAdd(&zex[(bq * 4 + i) * 20 + cq * 4 + c], acc[i][c]);
            }
            __syncthreads();                                   // B3

            if (tid < 256) {                 // elementwise: one (batch,unit) each
                const float* zp = zex + eb * 20 + eu * 4;
                const float* bp = biasS + eu * 4;
                float zi = zp[0] + bp[0], zf = zp[1] + bp[1];
                float zg = zp[2] + bp[2], zo = zp[3] + bp[3];
                float ig = 1.f / (1.f + expf(-zi));
                float fg = 1.f / (1.f + expf(-zf));
                float gg = fmaxf(zg, 0.f);
                float og = 1.f / (1.f + expf(-zo));
                cst = fg * cst + ig * gg;
                hvs[eb * 4 + eu] = og * fmaxf(cst, 0.f);
            }
            __syncthreads();                                   // B4

            if (tid < 64) {                  // publish h1[s]: x4 write-through + drain
                v4f hv = *(const v4f*)(hvs + tid * 4);
                float* dst = h1ring + (size_t)(s % 3) * SLOT
                           + (size_t)(bg * 64 + tid) * HID + ug * 4;
                store_wt16(dst, hv);
                __builtin_amdgcn_s_waitcnt(0);
            } else {
                for (int i = tid - 64; i < 1280; i += 448) zex[i] = 0.f;  // for step s+1
            }
            __syncthreads();                                   // B5
            if (tid == 0) st_flag(myF, s + 1);
        }
    } else {
        // ---------------- LAYER 2 ----------------
        const int ks = tid >> 5;             // k-split 0..15, K-seg = 32
        const int bq = (tid >> 2) & 7;       // batch-quad in half, 0..7
        const int cq = tid & 3;
        const int kb4 = ks * 8;
        const int eb = tid >> 2, eu = tid & 3;   // ew map (tid<128)
        float cst[2] = {0.f, 0.f};

        for (int s = 0; s < T_SEQ; ++s) {
            if (tid < 64) {                  // wait h1[s] ready AND own group done s-1
                const int ta = s + 1, tb = s;
                for (;;) {
                    int a = ld_flag(grpF1 + tid);
                    int b = ld_flag(grpF2 + tid);
                    if (__all((a >= ta) && (b >= tb))) break;
                    __builtin_amdgcn_s_sleep(2);
                }
                __builtin_amdgcn_fence(__ATOMIC_ACQUIRE, "agent");
            }
            __syncthreads();                                   // B1

            const float* h1s = h1ring + (size_t)(s % 3) * SLOT + (size_t)bg * 64 * HID;
            const float* h2s = h2b + (size_t)((s + 1) & 1) * SLOT + (size_t)bg * 64 * HID;
            float*       h2o = h2b + (size_t)(s & 1) * SLOT + (size_t)bg * 64 * HID;

            #pragma unroll
            for (int hf = 0; hf < 2; ++hf) {   // two 32-batch halves
                const float* pa = h1s + hf * 32 * HID;
                const float* pb = h2s + hf * 32 * HID;
                #pragma unroll
                for (int j = 0; j < 8; ++j) {  // stage [h1|h2] -> hs[32][520]
                    const int idx = tid + j * 512, r = idx >> 7, c4 = idx & 127;
                    v4f v;
                    if (c4 < 64) v = *(const v4f*)(pa + r * HID + c4 * 4);
                    else if (s == 0) { v4f z = {0.f, 0.f, 0.f, 0.f}; v = z; }
                    else v = *(const v4f*)(pb + r * HID + (c4 - 64) * 4);
                    *(v4f*)(hs + r * H2STR + c4 * 4) = v;
                }
                __syncthreads();                               // B2

                {
                    const v4f* A0 = (const v4f*)(hs + (bq * 4 + 0) * H2STR) + kb4;
                    const v4f* A1 = (const v4f*)(hs + (bq * 4 + 1) * H2STR) + kb4;
                    const v4f* A2 = (const v4f*)(hs + (bq * 4 + 2) * H2STR) + kb4;
                    const v4f* A3 = (const v4f*)(hs + (bq * 4 + 3) * H2STR) + kb4;
                    const v4f* W0 = (const v4f*)(wT + (cq * 4 + 0) * WSTR) + kb4;
                    const v4f* W1v = (const v4f*)(wT + (cq * 4 + 1) * WSTR) + kb4;
                    const v4f* W2v = (const v4f*)(wT + (cq * 4 + 2) * WSTR) + kb4;
                    const v4f* W3v = (const v4f*)(wT + (cq * 4 + 3) * WSTR) + kb4;
                    float acc[4][4] = {};
                    #pragma unroll
                    for (int j = 0; j < 8; ++j) {
                        v4f a0 = A0[j], a1 = A1[j], a2 = A2[j], a3 = A3[j];
                        v4f w0 = W0[j], w1 = W1v[j], w2 = W2v[j], w3 = W3v[j];
                        acc[0][0] = dot4(acc[0][0], a0, w0); acc[0][1] = dot4(acc[0][1], a0, w1);
                        acc[0][2] = dot4(acc[0][2], a0, w2); acc[0][3] = dot4(acc[0][3], a0, w3);
                        acc[1][0] = dot4(acc[1][0], a1, w0); acc[1][1] = dot4(acc[1][1], a1, w1);
                        acc[1][2] = dot4(acc[1][2], a1, w2); acc[1][3] = dot4(acc[1][3], a1, w3);
                        acc[2][0] = dot4(acc[2][0], a2, w0); acc[2][1] = dot4(acc[2][1], a2, w1);
                        acc[2][2] = dot4(acc[2][2], a2, w2); acc[2][3] = dot4(acc[2][3], a2, w3);
                        acc[3][0] = dot4(acc[3][0], a3, w0); acc[3][1] = dot4(acc[3][1], a3, w1);
                        acc[3][2] = dot4(acc[3][2], a3, w2); acc[3][3] = dot4(acc[3][3], a3, w3);
                    }
                    #pragma unroll
                    for (int i = 0; i < 4; ++i)
                        #pragma unroll
                        for (int c = 0; c < 4; ++c)
                            atomicAdd(&zex[(bq * 4 + i) * 20 + cq * 4 + c], acc[i][c]);
                }
                __syncthreads();                               // B3

                if (tid < 128) {
                    const float* zp = zex + eb * 20 + eu * 4;
                    const float* bp = biasS + eu * 4;
                    float zi = zp[0] + bp[0], zf = zp[1] + bp[1];
                    float zg = zp[2] + bp[2], zo = zp[3] + bp[3];
                    float ig = 1.f / (1.f + expf(-zi));
                    float fg = 1.f / (1.f + expf(-zf));
                    float gg = fmaxf(zg, 0.f);
                    float og = 1.f / (1.f + expf(-zo));
                    cst[hf] = fg * cst[hf] + ig * gg;
                    hvs[eb * 4 + eu] = og * fmaxf(cst[hf], 0.f);
                }
                __syncthreads();                               // B4

                if (tid < 32) {
                    v4f hv = *(const v4f*)(hvs + tid * 4);
                    float* dst = h2o + (size_t)(hf * 32 + tid) * HID + ug * 4;
                    store_wt16(dst, hv);
                    __builtin_amdgcn_s_waitcnt(0);
                } else if (tid >= 64) {
                    for (int i = tid - 64; i < 1280; i += 448) zex[i] = 0.f;
                }
                __syncthreads();                               // B5
            }
            if (tid == 0) st_flag(myF, s + 1);
        }
    }
}

// Dense + softmax: one block per batch row.
__global__ __launch_bounds__(256)
void dense_softmax_kernel(const float* __restrict__ h, const float* __restrict__ Wd,
                          const float* __restrict__ bd, float* __restrict__ out)
{
    __shared__ float hsd[HID];
    __shared__ float red[256];
    const int b = blockIdx.x, tid = threadIdx.x;

    hsd[tid] = h[b * HID + tid];
    __syncthreads();

    float a0 = 0.f, a1 = 0.f, a2 = 0.f, a3 = 0.f;
    const bool has3 = (tid < DOUT - 768);
    const int c3 = has3 ? (tid + 768) : 0;
    for (int k = 0; k < HID; ++k) {
        const float hk = hsd[k];
        const float* wr = Wd + (size_t)k * DOUT;
        a0 = fmaf(hk, wr[tid],       a0);
        a1 = fmaf(hk, wr[tid + 256], a1);
        a2 = fmaf(hk, wr[tid + 512], a2);
        a3 = fmaf(hk, wr[c3],        a3);
    }
    a0 += bd[tid]; a1 += bd[tid + 256]; a2 += bd[tid + 512];
    if (has3) a3 += bd[tid + 768];

    float m = fmaxf(fmaxf(a0, a1), a2);
    if (has3) m = fmaxf(m, a3);
    red[tid] = m; __syncthreads();
    for (int s = 128; s > 0; s >>= 1) {
        if (tid < s) red[tid] = fmaxf(red[tid], red[tid + s]);
        __syncthreads();
    }
    const float M = red[0];
    __syncthreads();

    float e0 = expf(a0 - M), e1 = expf(a1 - M), e2 = expf(a2 - M);
    float e3 = has3 ? expf(a3 - M) : 0.f;
    red[tid] = e0 + e1 + e2 + e3; __syncthreads();
    for (int s = 128; s > 0; s >>= 1) {
        if (tid < s) red[tid] += red[tid + s];
        __syncthreads();
    }
    const float inv = 1.f / red[0];

    float* o = out + (size_t)b * DOUT;
    o[tid] = e0 * inv;
    o[tid + 256] = e1 * inv;
    o[tid + 512] = e2 * inv;
    if (has3) o[tid + 768] = e3 * inv;
}

extern "C" void kernel_launch(void* const* d_in, const int* in_sizes, int n_in,
                              void* d_out, int out_size, void* d_ws, size_t ws_size,
                              hipStream_t stream)
{
    const float* x  = (const float*)d_in[0];
    const float* W1 = (const float*)d_in[1];
    const float* U1 = (const float*)d_in[2];
    const float* b1 = (const float*)d_in[3];
    const float* W2 = (const float*)d_in[4];
    const float* U2 = (const float*)d_in[5];
    const float* b2 = (const float*)d_in[6];
    const float* Wd = (const float*)d_in[7];
    const float* bd = (const float*)d_in[8];
    float* out = (float*)d_out;
    float* ws  = (float*)d_ws;

    // h1 ring (3 x 32768 floats) lives in d_out (128*1000 = 128000 floats);
    // fully overwritten by dense_softmax afterwards, which reads only ws.
    float* h1ring = out;

    // flags must start at 0 (ws is poisoned 0xAA each call)
    hipMemsetAsync(ws, 0, 1024, stream);

    hipFuncSetAttribute((const void*)lstm_pipe_kernel,
                        hipFuncAttributeMaxDynamicSharedMemorySize, (int)SMEM_BYTES);

    void* args[] = { (void*)&x, (void*)&W1, (void*)&U1, (void*)&b1,
                     (void*)&W2, (void*)&U2, (void*)&b2,
                     (void*)&h1ring, (void*)&ws };
    hipLaunchCooperativeKernel((const void*)lstm_pipe_kernel,
                               dim3(256), dim3(512), args, (int)SMEM_BYTES, stream);

    // final h2 = slot (1023 & 1) = 1
    const float* h2final = ws + 256 + SLOT;
    hipLaunchKernelGGL(dense_softmax_kernel, dim3(128), dim3(256), 0, stream,
                       h2final, Wd, bd, out);
}

// Round 7
// 22316.608 us; speedup vs baseline: 3.3176x; 1.5773x over previous
//
#include <hip/hip_runtime.h>
#include <math.h>

static constexpr int T_SEQ = 1024;
static constexpr int DIN = 128;
static constexpr int HID = 256;
static constexpr int DOUT = 1000;
static constexpr int NB = 128;
static constexpr int SLOT = HID * NB;   // 32768 floats per h slot, [H][B]-major

// LDS layout (floats). Strides chosen: %4==0 (v4f) and %8==4 (4-row lane step
// lands on 2 bank-quads -> ~4-way A-read aliasing instead of 8-way).
static constexpr int W1STR = 388;              // K=384 + 4
static constexpr int W2STR = 516;              // K=512 + 4
static constexpr int ASTR  = 652;              // 640 + 12: [x 0:128 | h1 128:384 | h2 384:640]
static constexpr int OFF_W2 = 16 * W1STR;            // 6208
static constexpr int OFF_A  = OFF_W2 + 16 * W2STR;   // 14464
static constexpr int OFF_Z1 = OFF_A + 32 * ASTR;     // 35328 (zex1 [32][20])
static constexpr int OFF_Z2 = OFF_Z1 + 640;          // zex2
static constexpr int OFF_V1 = OFF_Z2 + 640;          // hvs1 [4][32]
static constexpr int OFF_V2 = OFF_V1 + 128;          // hvs2
static constexpr int OFF_B1 = OFF_V2 + 128;          // bias1 [16]
static constexpr int OFF_B2 = OFF_B1 + 16;           // bias2 [16]
static constexpr size_t SMEM_BYTES = (size_t)(OFF_B2 + 16) * 4;   // 147,584 B (1 block/CU)

typedef float v4f __attribute__((ext_vector_type(4)));
typedef unsigned long long u64t;

#define SCOPE_AGENT __HIP_MEMORY_SCOPE_AGENT

__device__ __forceinline__ int ld_flag(const int* p) {
    return __hip_atomic_load(p, __ATOMIC_RELAXED, SCOPE_AGENT);
}
__device__ __forceinline__ void st_flag(int* p, int v) {
    __hip_atomic_store(p, v, __ATOMIC_RELAXED, SCOPE_AGENT);
}
__device__ __forceinline__ u64t ld_cp8(const u64t* p) {
    return __hip_atomic_load(p, __ATOMIC_RELAXED, SCOPE_AGENT);
}
__device__ __forceinline__ void st_cp8(u64t* p, u64t v) {
    __hip_atomic_store(p, v, __ATOMIC_RELAXED, SCOPE_AGENT);
}

union F2U { u64t u; float f[2]; };

__device__ __forceinline__ float dot4(float acc, v4f va, v4f vb) {
    return fmaf(va.x, vb.x, fmaf(va.y, vb.y,
           fmaf(va.z, vb.z, fmaf(va.w, vb.w, acc))));
}

// Fused 2-layer LSTM, 256 blocks x 512 threads, 1 block/CU (LDS 147.6 KB).
// Block (bg,ug): waves 0-3 = layer-1 step p, waves 4-7 = layer-2 step p-1,
// lockstep over phases p=0..1024. ONE poll + ONE flag per block per phase:
// flag >= p certifies the whole previous phase (h1[p-1] AND h2[p-2] published
// group-wide) -> double-buffered h1/h2 are safe (overwrite at p+2 gated by
// flag >= p+2). Shared [32][x|h1|h2] LDS tile staged once, read by both
// layers. h buffers [H][B]-major at the coherence point (sc0sc1 atomics,
// coalesced 8B); acquire fence after poll (R2/R4-proven consumer pattern).
// NOTE R5/R6 lesson: check the cooperative-launch RETURN CODE — a rejected
// launch (grid > validated co-residency) fails silently otherwise.
__global__ __launch_bounds__(512)
void lstm_fused_kernel(const float* __restrict__ x,
                       const float* __restrict__ W1, const float* __restrict__ U1,
                       const float* __restrict__ b1,
                       const float* __restrict__ W2, const float* __restrict__ U2,
                       const float* __restrict__ b2,
                       float* __restrict__ h1b,   // 2*SLOT (d_out scratch), [slot][H][B]
                       float* __restrict__ ws)    // [1024 ints: flags][2*SLOT h2 [H][B]]
{
    extern __shared__ float smem[];
    float* wT1  = smem;
    float* wT2  = smem + OFF_W2;
    float* hsA  = smem + OFF_A;
    float* zex1 = smem + OFF_Z1;    // zex1|zex2 contiguous (1280 floats)
    float* zex2 = smem + OFF_Z2;
    float* hvs1 = smem + OFF_V1;
    float* hvs2 = smem + OFF_V2;
    float* bia1 = smem + OFF_B1;
    float* bia2 = smem + OFF_B2;

    int*   F   = (int*)ws;          // 4 groups x 128 ints (first 64 used each)
    float* h2b = ws + 1024;

    const int tid = threadIdx.x;
    const int bid = blockIdx.x;
    const int bg  = bid >> 6;       // batch group 0..3 (batches bg*32..+31)
    const int ug  = bid & 63;       // unit group (units ug*4..+3)
    int* grpF = F + bg * 128;
    int* myF  = grpF + ug;

    // ---- one-time: both weight tiles (transposed) + biases into LDS ----
    {
        const int half = tid >> 8;          // 0: L1 weights, 1: L2 weights
        const int t    = tid & 255;
        const int K    = half ? 512 : 384;
        const int len0 = half ? 256 : 128;
        const float* Wp = half ? W2 : W1;
        const float* Up = half ? U2 : U1;
        float* wt = half ? wT2 : wT1;
        const int wstr = half ? W2STR : W1STR;
        for (int c = 0; c < 16; ++c) {
            const int col = (c & 3) * HID + ug * 4 + (c >> 2);   // gate-major
            for (int k = t; k < K; k += 256)
                wt[c * wstr + k] = (k < len0) ? Wp[(size_t)k * (4 * HID) + col]
                                              : Up[(size_t)(k - len0) * (4 * HID) + col];
        }
    }
    if (tid < 16)                     bia1[tid] = b1[(tid & 3) * HID + ug * 4 + (tid >> 2)];
    else if (tid >= 256 && tid < 272) { const int t = tid - 256;
                                        bia2[t]  = b2[(t & 3) * HID + ug * 4 + (t >> 2)]; }
    for (int i = tid; i < 1280; i += 512) zex1[i] = 0.f;
    __syncthreads();

    // GEMM mapping per 256-thread half: 4 col-quads x 8 batch-quads x 8 k-splits
    const int t  = tid & 255;
    const int cq = t & 3;
    const int bq = (t >> 2) & 7;
    const int ks = t >> 5;            // 0..7
    float cst = 0.f;                  // L1 state (tid<128) or L2 state (256<=tid<384)

    for (int p = 0; p <= T_SEQ; ++p) {
        // prestage x_p -> hsA[.][0:128)   (read-only input, cached loads)
        if (p < T_SEQ) {
            #pragma unroll
            for (int it = 0; it < 2; ++it) {
                const int idx = tid + it * 512, r = idx >> 5, c4 = idx & 31;
                v4f v = *(const v4f*)(x + ((size_t)(bg * 32 + r) * T_SEQ + p) * DIN + c4 * 4);
                *(v4f*)(hsA + r * ASTR + c4 * 4) = v;
            }
        }
        // wave0: all 64 group blocks finished phase p-1; then invalidate caches
        if (tid < 64) {
            for (;;) {
                int a = ld_flag(grpF + tid);
                if (__all(a >= p)) break;
                __builtin_amdgcn_s_sleep(4);
            }
            __builtin_amdgcn_fence(__ATOMIC_ACQUIRE, "agent");
        }
        __syncthreads();                                    // B1

        // stage h1[p-1] -> cols 128:384 and h2[p-2] -> cols 384:640 (transpose)
        {
            const u64t* hp1 = (const u64t*)(h1b + (size_t)((p + 1) & 1) * SLOT + bg * 32);
            #pragma unroll
            for (int it = 0; it < 8; ++it) {
                const int idx = tid + it * 512, k = idx >> 4, bb = idx & 15;
                F2U v; v.u = (p == 0) ? 0ull : ld_cp8(hp1 + (size_t)k * 64 + bb);
                hsA[(bb * 2 + 0) * ASTR + 128 + k] = v.f[0];
                hsA[(bb * 2 + 1) * ASTR + 128 + k] = v.f[1];
            }
            const u64t* hp2 = (const u64t*)(h2b + (size_t)(p & 1) * SLOT + bg * 32);
            #pragma unroll
            for (int it = 0; it < 8; ++it) {
                const int idx = tid + it * 512, k = idx >> 4, bb = idx & 15;
                F2U v; v.u = (p <= 1) ? 0ull : ld_cp8(hp2 + (size_t)k * 64 + bb);
                hsA[(bb * 2 + 0) * ASTR + 384 + k] = v.f[0];
                hsA[(bb * 2 + 1) * ASTR + 384 + k] = v.f[1];
            }
        }
        __syncthreads();                                    // B2

        // GEMMs: L1-half (K=384, cols 0:384), L2-half (K=512, cols 128:640)
        if (tid < 256) {
            if (p < T_SEQ) {
                const float* Ab = hsA + (bq * 4) * ASTR + ks * 48;
                const float* Wb = wT1 + (cq * 4) * W1STR + ks * 48;
                float acc[4][4] = {};
                #pragma unroll
                for (int j = 0; j < 12; ++j) {
                    v4f a0 = *(const v4f*)(Ab + 0 * ASTR + j * 4);
                    v4f a1 = *(const v4f*)(Ab + 1 * ASTR + j * 4);
                    v4f a2 = *(const v4f*)(Ab + 2 * ASTR + j * 4);
                    v4f a3 = *(const v4f*)(Ab + 3 * ASTR + j * 4);
                    v4f w0 = *(const v4f*)(Wb + 0 * W1STR + j * 4);
                    v4f w1 = *(const v4f*)(Wb + 1 * W1STR + j * 4);
                    v4f w2 = *(const v4f*)(Wb + 2 * W1STR + j * 4);
                    v4f w3 = *(const v4f*)(Wb + 3 * W1STR + j * 4);
                    acc[0][0]=dot4(acc[0][0],a0,w0); acc[0][1]=dot4(acc[0][1],a0,w1);
                    acc[0][2]=dot4(acc[0][2],a0,w2); acc[0][3]=dot4(acc[0][3],a0,w3);
                    acc[1][0]=dot4(acc[1][0],a1,w0); acc[1][1]=dot4(acc[1][1],a1,w1);
                    acc[1][2]=dot4(acc[1][2],a1,w2); acc[1][3]=dot4(acc[1][3],a1,w3);
                    acc[2][0]=dot4(acc[2][0],a2,w0); acc[2][1]=dot4(acc[2][1],a2,w1);
                    acc[2][2]=dot4(acc[2][2],a2,w2); acc[2][3]=dot4(acc[2][3],a2,w3);
                    acc[3][0]=dot4(acc[3][0],a3,w0); acc[3][1]=dot4(acc[3][1],a3,w1);
                    acc[3][2]=dot4(acc[3][2],a3,w2); acc[3][3]=dot4(acc[3][3],a3,w3);
                }
                #pragma unroll
                for (int i = 0; i < 4; ++i)
                    #pragma unroll
                    for (int c = 0; c < 4; ++c)
                        atomicAdd(&zex1[(bq * 4 + i) * 20 + cq * 4 + c], acc[i][c]);
            }
        } else {
            if (p >= 1) {
                const float* Ab = hsA + (bq * 4) * ASTR + 128 + ks * 64;
                const float* Wb = wT2 + (cq * 4) * W2STR + ks * 64;
                float acc[4][4] = {};
                #pragma unroll
                for (int j = 0; j < 16; ++j) {
                    v4f a0 = *(const v4f*)(Ab + 0 * ASTR + j * 4);
                    v4f a1 = *(const v4f*)(Ab + 1 * ASTR + j * 4);
                    v4f a2 = *(const v4f*)(Ab + 2 * ASTR + j * 4);
                    v4f a3 = *(const v4f*)(Ab + 3 * ASTR + j * 4);
                    v4f w0 = *(const v4f*)(Wb + 0 * W2STR + j * 4);
                    v4f w1 = *(const v4f*)(Wb + 1 * W2STR + j * 4);
                    v4f w2 = *(const v4f*)(Wb + 2 * W2STR + j * 4);
                    v4f w3 = *(const v4f*)(Wb + 3 * W2STR + j * 4);
                    acc[0][0]=dot4(acc[0][0],a0,w0); acc[0][1]=dot4(acc[0][1],a0,w1);
                    acc[0][2]=dot4(acc[0][2],a0,w2); acc[0][3]=dot4(acc[0][3],a0,w3);
                    acc[1][0]=dot4(acc[1][0],a1,w0); acc[1][1]=dot4(acc[1][1],a1,w1);
                    acc[1][2]=dot4(acc[1][2],a1,w2); acc[1][3]=dot4(acc[1][3],a1,w3);
                    acc[2][0]=dot4(acc[2][0],a2,w0); acc[2][1]=dot4(acc[2][1],a2,w1);
                    acc[2][2]=dot4(acc[2][2],a2,w2); acc[2][3]=dot4(acc[2][3],a2,w3);
                    acc[3][0]=dot4(acc[3][0],a3,w0); acc[3][1]=dot4(acc[3][1],a3,w1);
                    acc[3][2]=dot4(acc[3][2],a3,w2); acc[3][3]=dot4(acc[3][3],a3,w3);
                }
                #pragma unroll
                for (int i = 0; i < 4; ++i)
                    #pragma unroll
                    for (int c = 0; c < 4; ++c)
                        atomicAdd(&zex2[(bq * 4 + i) * 20 + cq * 4 + c], acc[i][c]);
            }
        }
        __syncthreads();                                    // B3

        // elementwise: L1 on tids 0..127 (step p), L2 on tids 256..383 (step p-1)
        if (tid < 128) {
            if (p < T_SEQ) {
                const int eb = tid >> 2, eu = tid & 3;
                const float* zp = zex1 + eb * 20 + eu * 4;
                const float* bp = bia1 + eu * 4;
                float zi = zp[0] + bp[0], zf = zp[1] + bp[1];
                float zg = zp[2] + bp[2], zo = zp[3] + bp[3];
                float ig = 1.f / (1.f + expf(-zi));
                float fg = 1.f / (1.f + expf(-zf));
                float gg = fmaxf(zg, 0.f);
                float og = 1.f / (1.f + expf(-zo));
                cst = fg * cst + ig * gg;
                hvs1[eu * 32 + eb] = og * fmaxf(cst, 0.f);
            }
        } else if (tid >= 256 && tid < 384) {
            if (p >= 1) {
                const int t2 = tid - 256, eb = t2 >> 2, eu = t2 & 3;
                const float* zp = zex2 + eb * 20 + eu * 4;
                const float* bp = bia2 + eu * 4;
                float zi = zp[0] + bp[0], zf = zp[1] + bp[1];
                float zg = zp[2] + bp[2], zo = zp[3] + bp[3];
                float ig = 1.f / (1.f + expf(-zi));
                float fg = 1.f / (1.f + expf(-zf));
                float gg = fmaxf(zg, 0.f);
                float og = 1.f / (1.f + expf(-zo));
                cst = fg * cst + ig * gg;
                hvs2[eu * 32 + eb] = og * fmaxf(cst, 0.f);
            }
        }
        __syncthreads();                                    // B4

        // publish h1[p] (tids 0..63) and h2[p-1] (tids 256..319); others zero zex
        if (tid < 64) {
            if (p < T_SEQ) {
                const int u = tid >> 4, pr = tid & 15;
                F2U v; v.f[0] = hvs1[u * 32 + pr * 2]; v.f[1] = hvs1[u * 32 + pr * 2 + 1];
                st_cp8((u64t*)(h1b + (size_t)(p & 1) * SLOT
                               + (size_t)(ug * 4 + u) * NB + bg * 32) + pr, v.u);
                __builtin_amdgcn_s_waitcnt(0);
            }
        } else if (tid >= 256 && tid < 320) {
            if (p >= 1) {
                const int t2 = tid - 256, u = t2 >> 4, pr = t2 & 15;
                F2U v; v.f[0] = hvs2[u * 32 + pr * 2]; v.f[1] = hvs2[u * 32 + pr * 2 + 1];
                st_cp8((u64t*)(h2b + (size_t)((p + 1) & 1) * SLOT
                               + (size_t)(ug * 4 + u) * NB + bg * 32) + pr, v.u);
                __builtin_amdgcn_s_waitcnt(0);
            }
        } else if (tid >= 384) {
            for (int i = tid - 384; i < 1280; i += 128) zex1[i] = 0.f;
        }
        __syncthreads();                                    // B5
        if (tid == 0) st_flag(myF, p + 1);
    }
    // final h2 = step 1023 -> slot 1, at ws + 1024 + SLOT
}

// Dense + softmax: one block per batch row. h2 is [H][B]-major.
__global__ __launch_bounds__(256)
void dense_softmax_kernel(const float* __restrict__ h, const float* __restrict__ Wd,
                          const float* __restrict__ bd, float* __restrict__ out)
{
    __shared__ float hsd[HID];
    __shared__ float red[256];
    const int b = blockIdx.x, tid = threadIdx.x;

    hsd[tid] = h[(size_t)tid * NB + b];
    __syncthreads();

    float a0 = 0.f, a1 = 0.f, a2 = 0.f, a3 = 0.f;
    const bool has3 = (tid < DOUT - 768);
    const int c3 = has3 ? (tid + 768) : 0;
    for (int k = 0; k < HID; ++k) {
        const float hk = hsd[k];
        const float* wr = Wd + (size_t)k * DOUT;
        a0 = fmaf(hk, wr[tid],       a0);
        a1 = fmaf(hk, wr[tid + 256], a1);
        a2 = fmaf(hk, wr[tid + 512], a2);
        a3 = fmaf(hk, wr[c3],        a3);
    }
    a0 += bd[tid]; a1 += bd[tid + 256]; a2 += bd[tid + 512];
    if (has3) a3 += bd[tid + 768];

    float m = fmaxf(fmaxf(a0, a1), a2);
    if (has3) m = fmaxf(m, a3);
    red[tid] = m; __syncthreads();
    for (int s = 128; s > 0; s >>= 1) {
        if (tid < s) red[tid] = fmaxf(red[tid], red[tid + s]);
        __syncthreads();
    }
    const float M = red[0];
    __syncthreads();

    float e0 = expf(a0 - M), e1 = expf(a1 - M), e2 = expf(a2 - M);
    float e3 = has3 ? expf(a3 - M) : 0.f;
    red[tid] = e0 + e1 + e2 + e3; __syncthreads();
    for (int s = 128; s > 0; s >>= 1) {
        if (tid < s) red[tid] += red[tid + s];
        __syncthreads();
    }
    const float inv = 1.f / red[0];

    float* o = out + (size_t)b * DOUT;
    o[tid] = e0 * inv;
    o[tid + 256] = e1 * inv;
    o[tid + 512] = e2 * inv;
    if (has3) o[tid + 768] = e3 * inv;
}

extern "C" void kernel_launch(void* const* d_in, const int* in_sizes, int n_in,
                              void* d_out, int out_size, void* d_ws, size_t ws_size,
                              hipStream_t stream)
{
    const float* x  = (const float*)d_in[0];
    const float* W1 = (const float*)d_in[1];
    const float* U1 = (const float*)d_in[2];
    const float* b1 = (const float*)d_in[3];
    const float* W2 = (const float*)d_in[4];
    const float* U2 = (const float*)d_in[5];
    const float* b2 = (const float*)d_in[6];
    const float* Wd = (const float*)d_in[7];
    const float* bd = (const float*)d_in[8];
    float* out = (float*)d_out;
    float* ws  = (float*)d_ws;

    // h1: 2 slots x 32768 floats in d_out (128000 floats), [slot][H][B];
    // fully overwritten by dense_softmax afterwards (which reads only ws).
    float* h1b = out;

    // flag region (ints 0..1023; groups at bg*128) must start at 0
    hipMemsetAsync(ws, 0, 4096, stream);

    hipFuncSetAttribute((const void*)lstm_fused_kernel,
                        hipFuncAttributeMaxDynamicSharedMemorySize, (int)SMEM_BYTES);

    void* args[] = { (void*)&x, (void*)&W1, (void*)&U1, (void*)&b1,
                     (void*)&W2, (void*)&U2, (void*)&b2,
                     (void*)&h1b, (void*)&ws };
    hipError_t err = hipLaunchCooperativeKernel((const void*)lstm_fused_kernel,
                                                dim3(256), dim3(512), args,
                                                (int)SMEM_BYTES, stream);
    if (err != hipSuccess) {
        // R5/R6 failed silently on a rejected cooperative launch. Fallback:
        // 256 blocks at 1 block/CU are co-resident by resource constraints
        // (147.6KB LDS forbids 2/CU; 256 CUs available), so a plain launch
        // preserves the co-residency the flag protocol needs.
        hipLaunchKernelGGL(lstm_fused_kernel, dim3(256), dim3(512),
                           (int)SMEM_BYTES, stream,
                           x, W1, U1, b1, W2, U2, b2, h1b, ws);
    }

    const float* h2final = ws + 1024 + SLOT;   // slot 1 = h2[1023]
    hipLaunchKernelGGL(dense_softmax_kernel, dim3(128), dim3(256), 0, stream,
                       h2final, Wd, bd, out);
}

// Round 8
// 20085.841 us; speedup vs baseline: 3.6860x; 1.1111x over previous
//
#include <hip/hip_runtime.h>
#include <math.h>

static constexpr int T_SEQ = 1024;
static constexpr int DIN = 128;
static constexpr int HID = 256;
static constexpr int DOUT = 1000;
static constexpr int NB = 128;
static constexpr int SLOT = HID * NB;   // 32768 floats per h slot, [H][B]-major

// LDS layout (floats) — strides unchanged from R7 (measured conflicts were
// only ~0.7us/phase, not the wall).
static constexpr int W1STR = 388;              // K=384 + 4
static constexpr int W2STR = 516;              // K=512 + 4
static constexpr int ASTR  = 652;              // [x 0:128 | h1 128:384 | h2 384:640] + 12
static constexpr int OFF_W2 = 16 * W1STR;            // 6208
static constexpr int OFF_A  = OFF_W2 + 16 * W2STR;   // 14464
static constexpr int OFF_Z  = OFF_A + 32 * ASTR;     // 35328: zex double-buffered 2x[zex1 640|zex2 640]
static constexpr int OFF_B1 = OFF_Z + 2560;          // bias1 [16]
static constexpr int OFF_B2 = OFF_B1 + 16;           // bias2 [16]
static constexpr size_t SMEM_BYTES = (size_t)(OFF_B2 + 16) * 4;   // 151,680 B (1 block/CU)

typedef float v4f __attribute__((ext_vector_type(4)));
typedef unsigned long long u64t;

#define SCOPE_AGENT __HIP_MEMORY_SCOPE_AGENT

__device__ __forceinline__ int ld_flag(const int* p) {
    return __hip_atomic_load(p, __ATOMIC_RELAXED, SCOPE_AGENT);
}
__device__ __forceinline__ void st_flag(int* p, int v) {
    __hip_atomic_store(p, v, __ATOMIC_RELAXED, SCOPE_AGENT);
}
// 4B/8B write-through stores to the coherence point (producer side only).
// R8: consumer bulk loads are now CACHED (the post-poll acquire fence
// invalidates L1/L2 first — R4-proven). R7's per-lane sc0sc1 atomic LOADS
// were the suspected coherence-point service wall (~13us/phase idle).
__device__ __forceinline__ void st_cp4(float* p, float v) {
    __hip_atomic_store(p, v, __ATOMIC_RELAXED, SCOPE_AGENT);
}

union F2U { u64t u; float f[2]; };

__device__ __forceinline__ float dot4(float acc, v4f va, v4f vb) {
    return fmaf(va.x, vb.x, fmaf(va.y, vb.y,
           fmaf(va.z, vb.z, fmaf(va.w, vb.w, acc))));
}

// Fused 2-layer LSTM, 256 blocks x 512 threads, 1 block/CU (LDS 151.7 KB).
// Waves 0-3 = layer-1 step p, waves 4-7 = layer-2 step p-1, lockstep phases.
// One poll + one flag per block per phase. h buffers [H][B]-major:
// publish = coalesced sc0sc1 stores from ew registers; consume = CACHED 8B
// loads after fence(acquire, agent). zex double-buffered by phase parity so
// zeroing overlaps ew without an extra barrier. 4 barriers per phase.
__global__ __launch_bounds__(512)
void lstm_fused_kernel(const float* __restrict__ x,
                       const float* __restrict__ W1, const float* __restrict__ U1,
                       const float* __restrict__ b1,
                       const float* __restrict__ W2, const float* __restrict__ U2,
                       const float* __restrict__ b2,
                       float* __restrict__ h1b,   // 2*SLOT (d_out scratch), [slot][H][B]
                       float* __restrict__ ws)    // [1024 ints: flags][2*SLOT h2 [H][B]]
{
    extern __shared__ float smem[];
    float* wT1  = smem;
    float* wT2  = smem + OFF_W2;
    float* hsA  = smem + OFF_A;
    float* zbase = smem + OFF_Z;    // 2 x 1280 (zex1|zex2), parity-selected
    float* bia1 = smem + OFF_B1;
    float* bia2 = smem + OFF_B2;

    int*   F   = (int*)ws;          // 4 groups x 128 ints (first 64 used each)
    float* h2b = ws + 1024;

    const int tid = threadIdx.x;
    const int bid = blockIdx.x;
    const int bg  = bid >> 6;       // batch group 0..3 (batches bg*32..+31)
    const int ug  = bid & 63;       // unit group (units ug*4..+3)
    int* grpF = F + bg * 128;
    int* myF  = grpF + ug;

    // ---- one-time: both weight tiles (transposed) + biases into LDS ----
    {
        const int half = tid >> 8;          // 0: L1 weights, 1: L2 weights
        const int t    = tid & 255;
        const int K    = half ? 512 : 384;
        const int len0 = half ? 256 : 128;
        const float* Wp = half ? W2 : W1;
        const float* Up = half ? U2 : U1;
        float* wt = half ? wT2 : wT1;
        const int wstr = half ? W2STR : W1STR;
        for (int c = 0; c < 16; ++c) {
            const int col = (c & 3) * HID + ug * 4 + (c >> 2);   // gate-major
            for (int k = t; k < K; k += 256)
                wt[c * wstr + k] = (k < len0) ? Wp[(size_t)k * (4 * HID) + col]
                                              : Up[(size_t)(k - len0) * (4 * HID) + col];
        }
    }
    if (tid < 16)                     bia1[tid] = b1[(tid & 3) * HID + ug * 4 + (tid >> 2)];
    else if (tid >= 256 && tid < 272) { const int t = tid - 256;
                                        bia2[t]  = b2[(t & 3) * HID + ug * 4 + (t >> 2)]; }
    for (int i = tid; i < 2560; i += 512) zbase[i] = 0.f;   // both zex buffers
    __syncthreads();

    // GEMM mapping per 256-thread half: 4 col-quads x 8 batch-quads x 8 k-splits
    const int t  = tid & 255;
    const int cq = t & 3;
    const int bq = (t >> 2) & 7;
    const int ks = t >> 5;            // 0..7
    float cst = 0.f;                  // L1 state (tid<128) or L2 state (256<=tid<384)

    for (int p = 0; p <= T_SEQ; ++p) {
        float* zcur = zbase + (p & 1) * 1280;          // GEMM target / ew source
        float* znext = zbase + ((p + 1) & 1) * 1280;   // zeroed this phase

        // prestage x_p -> hsA[.][0:128)   (read-only input, cached loads)
        if (p < T_SEQ) {
            #pragma unroll
            for (int it = 0; it < 2; ++it) {
                const int idx = tid + it * 512, r = idx >> 5, c4 = idx & 31;
                v4f v = *(const v4f*)(x + ((size_t)(bg * 32 + r) * T_SEQ + p) * DIN + c4 * 4);
                *(v4f*)(hsA + r * ASTR + c4 * 4) = v;
            }
        }
        // wave0: all 64 group blocks finished phase p-1; then invalidate caches.
        // The fence is REQUIRED: consumer h loads below are cached.
        if (tid < 64) {
            for (;;) {
                int a = ld_flag(grpF + tid);
                if (__all(a >= p)) break;
                __builtin_amdgcn_s_sleep(1);
            }
            __builtin_amdgcn_fence(__ATOMIC_ACQUIRE, "agent");
        }
        __syncthreads();                                    // B1

        // stage h1[p-1] -> cols 128:384 and h2[p-2] -> cols 384:640 (transpose)
        // CACHED 8B loads (post-invalidate): coalesced, L2-served after first
        // touch per XCD — replaces R7's per-lane CP atomic loads.
        {
            const u64t* hp1 = (const u64t*)(h1b + (size_t)((p + 1) & 1) * SLOT + bg * 32);
            #pragma unroll
            for (int it = 0; it < 8; ++it) {
                const int idx = tid + it * 512, k = idx >> 4, bb = idx & 15;
                F2U v; v.u = (p == 0) ? 0ull : hp1[(size_t)k * 64 + bb];
                hsA[(bb * 2 + 0) * ASTR + 128 + k] = v.f[0];
                hsA[(bb * 2 + 1) * ASTR + 128 + k] = v.f[1];
            }
            const u64t* hp2 = (const u64t*)(h2b + (size_t)(p & 1) * SLOT + bg * 32);
            #pragma unroll
            for (int it = 0; it < 8; ++it) {
                const int idx = tid + it * 512, k = idx >> 4, bb = idx & 15;
                F2U v; v.u = (p <= 1) ? 0ull : hp2[(size_t)k * 64 + bb];
                hsA[(bb * 2 + 0) * ASTR + 384 + k] = v.f[0];
                hsA[(bb * 2 + 1) * ASTR + 384 + k] = v.f[1];
            }
        }
        __syncthreads();                                    // B2

        // GEMMs: L1-half (K=384, cols 0:384), L2-half (K=512, cols 128:640)
        if (tid < 256) {
            if (p < T_SEQ) {
                const float* Ab = hsA + (bq * 4) * ASTR + ks * 48;
                const float* Wb = wT1 + (cq * 4) * W1STR + ks * 48;
                float acc[4][4] = {};
                #pragma unroll
                for (int j = 0; j < 12; ++j) {
                    v4f a0 = *(const v4f*)(Ab + 0 * ASTR + j * 4);
                    v4f a1 = *(const v4f*)(Ab + 1 * ASTR + j * 4);
                    v4f a2 = *(const v4f*)(Ab + 2 * ASTR + j * 4);
                    v4f a3 = *(const v4f*)(Ab + 3 * ASTR + j * 4);
                    v4f w0 = *(const v4f*)(Wb + 0 * W1STR + j * 4);
                    v4f w1 = *(const v4f*)(Wb + 1 * W1STR + j * 4);
                    v4f w2 = *(const v4f*)(Wb + 2 * W1STR + j * 4);
                    v4f w3 = *(const v4f*)(Wb + 3 * W1STR + j * 4);
                    acc[0][0]=dot4(acc[0][0],a0,w0); acc[0][1]=dot4(acc[0][1],a0,w1);
                    acc[0][2]=dot4(acc[0][2],a0,w2); acc[0][3]=dot4(acc[0][3],a0,w3);
                    acc[1][0]=dot4(acc[1][0],a1,w0); acc[1][1]=dot4(acc[1][1],a1,w1);
                    acc[1][2]=dot4(acc[1][2],a1,w2); acc[1][3]=dot4(acc[1][3],a1,w3);
                    acc[2][0]=dot4(acc[2][0],a2,w0); acc[2][1]=dot4(acc[2][1],a2,w1);
                    acc[2][2]=dot4(acc[2][2],a2,w2); acc[2][3]=dot4(acc[2][3],a2,w3);
                    acc[3][0]=dot4(acc[3][0],a3,w0); acc[3][1]=dot4(acc[3][1],a3,w1);
                    acc[3][2]=dot4(acc[3][2],a3,w2); acc[3][3]=dot4(acc[3][3],a3,w3);
                }
                #pragma unroll
                for (int i = 0; i < 4; ++i)
                    #pragma unroll
                    for (int c = 0; c < 4; ++c)
                        atomicAdd(&zcur[(bq * 4 + i) * 20 + cq * 4 + c], acc[i][c]);
            }
        } else {
            if (p >= 1) {
                const float* Ab = hsA + (bq * 4) * ASTR + 128 + ks * 64;
                const float* Wb = wT2 + (cq * 4) * W2STR + ks * 64;
                float acc[4][4] = {};
                #pragma unroll
                for (int j = 0; j < 16; ++j) {
                    v4f a0 = *(const v4f*)(Ab + 0 * ASTR + j * 4);
                    v4f a1 = *(const v4f*)(Ab + 1 * ASTR + j * 4);
                    v4f a2 = *(const v4f*)(Ab + 2 * ASTR + j * 4);
                    v4f a3 = *(const v4f*)(Ab + 3 * ASTR + j * 4);
                    v4f w0 = *(const v4f*)(Wb + 0 * W2STR + j * 4);
                    v4f w1 = *(const v4f*)(Wb + 1 * W2STR + j * 4);
                    v4f w2 = *(const v4f*)(Wb + 2 * W2STR + j * 4);
                    v4f w3 = *(const v4f*)(Wb + 3 * W2STR + j * 4);
                    acc[0][0]=dot4(acc[0][0],a0,w0); acc[0][1]=dot4(acc[0][1],a0,w1);
                    acc[0][2]=dot4(acc[0][2],a0,w2); acc[0][3]=dot4(acc[0][3],a0,w3);
                    acc[1][0]=dot4(acc[1][0],a1,w0); acc[1][1]=dot4(acc[1][1],a1,w1);
                    acc[1][2]=dot4(acc[1][2],a1,w2); acc[1][3]=dot4(acc[1][3],a1,w3);
                    acc[2][0]=dot4(acc[2][0],a2,w0); acc[2][1]=dot4(acc[2][1],a2,w1);
                    acc[2][2]=dot4(acc[2][2],a2,w2); acc[2][3]=dot4(acc[2][3],a2,w3);
                    acc[3][0]=dot4(acc[3][0],a3,w0); acc[3][1]=dot4(acc[3][1],a3,w1);
                    acc[3][2]=dot4(acc[3][2],a3,w2); acc[3][3]=dot4(acc[3][3],a3,w3);
                }
                #pragma unroll
                for (int i = 0; i < 4; ++i)
                    #pragma unroll
                    for (int c = 0; c < 4; ++c)
                        atomicAdd(&zcur[640 + (bq * 4 + i) * 20 + cq * 4 + c], acc[i][c]);
            }
        }
        __syncthreads();                                    // B3

        // ew + DIRECT publish from registers (no hvs round-trip, no extra
        // barrier). Lane map eb=tid&31: 32 consecutive lanes publish one
        // contiguous 128B [H][B] row. Idle thread groups zero znext.
        if (tid < 128) {
            if (p < T_SEQ) {
                const int eb = tid & 31, eu = tid >> 5;
                const float* zp = zcur + eb * 20 + eu * 4;
                const float* bp = bia1 + eu * 4;
                float zi = zp[0] + bp[0], zf = zp[1] + bp[1];
                float zg = zp[2] + bp[2], zo = zp[3] + bp[3];
                float ig = 1.f / (1.f + expf(-zi));
                float fg = 1.f / (1.f + expf(-zf));
                float gg = fmaxf(zg, 0.f);
                float og = 1.f / (1.f + expf(-zo));
                cst = fg * cst + ig * gg;
                float hv = og * fmaxf(cst, 0.f);
                st_cp4(h1b + (size_t)(p & 1) * SLOT
                           + (size_t)(ug * 4 + eu) * NB + bg * 32 + eb, hv);
                __builtin_amdgcn_s_waitcnt(0);
            }
        } else if (tid < 256) {
            const int t0 = tid - 128;
            #pragma unroll
            for (int i = 0; i < 5; ++i) znext[t0 + i * 128] = 0.f;
        } else if (tid < 384) {
            if (p >= 1) {
                const int t2 = tid - 256, eb = t2 & 31, eu = t2 >> 5;
                const float* zp = zcur + 640 + eb * 20 + eu * 4;
                const float* bp = bia2 + eu * 4;
                float zi = zp[0] + bp[0], zf = zp[1] + bp[1];
                float zg = zp[2] + bp[2], zo = zp[3] + bp[3];
                float ig = 1.f / (1.f + expf(-zi));
                float fg = 1.f / (1.f + expf(-zf));
                float gg = fmaxf(zg, 0.f);
                float og = 1.f / (1.f + expf(-zo));
                cst = fg * cst + ig * gg;
                float hv = og * fmaxf(cst, 0.f);
                st_cp4(h2b + (size_t)((p + 1) & 1) * SLOT
                           + (size_t)(ug * 4 + eu) * NB + bg * 32 + eb, hv);
                __builtin_amdgcn_s_waitcnt(0);
            }
        } else {
            const int t0 = tid - 384;
            #pragma unroll
            for (int i = 0; i < 5; ++i) znext[640 + t0 + i * 128] = 0.f;
        }
        __syncthreads();                                    // B4
        if (tid == 0) st_flag(myF, p + 1);
    }
    // final h2 = step 1023 -> slot 1, at ws + 1024 + SLOT
}

// Dense + softmax: one block per batch row. h2 is [H][B]-major.
__global__ __launch_bounds__(256)
void dense_softmax_kernel(const float* __restrict__ h, const float* __restrict__ Wd,
                          const float* __restrict__ bd, float* __restrict__ out)
{
    __shared__ float hsd[HID];
    __shared__ float red[256];
    const int b = blockIdx.x, tid = threadIdx.x;

    hsd[tid] = h[(size_t)tid * NB + b];
    __syncthreads();

    float a0 = 0.f, a1 = 0.f, a2 = 0.f, a3 = 0.f;
    const bool has3 = (tid < DOUT - 768);
    const int c3 = has3 ? (tid + 768) : 0;
    for (int k = 0; k < HID; ++k) {
        const float hk = hsd[k];
        const float* wr = Wd + (size_t)k * DOUT;
        a0 = fmaf(hk, wr[tid],       a0);
        a1 = fmaf(hk, wr[tid + 256], a1);
        a2 = fmaf(hk, wr[tid + 512], a2);
        a3 = fmaf(hk, wr[c3],        a3);
    }
    a0 += bd[tid]; a1 += bd[tid + 256]; a2 += bd[tid + 512];
    if (has3) a3 += bd[tid + 768];

    float m = fmaxf(fmaxf(a0, a1), a2);
    if (has3) m = fmaxf(m, a3);
    red[tid] = m; __syncthreads();
    for (int s = 128; s > 0; s >>= 1) {
        if (tid < s) red[tid] = fmaxf(red[tid], red[tid + s]);
        __syncthreads();
    }
    const float M = red[0];
    __syncthreads();

    float e0 = expf(a0 - M), e1 = expf(a1 - M), e2 = expf(a2 - M);
    float e3 = has3 ? expf(a3 - M) : 0.f;
    red[tid] = e0 + e1 + e2 + e3; __syncthreads();
    for (int s = 128; s > 0; s >>= 1) {
        if (tid < s) red[tid] += red[tid + s];
        __syncthreads();
    }
    const float inv = 1.f / red[0];

    float* o = out + (size_t)b * DOUT;
    o[tid] = e0 * inv;
    o[tid + 256] = e1 * inv;
    o[tid + 512] = e2 * inv;
    if (has3) o[tid + 768] = e3 * inv;
}

extern "C" void kernel_launch(void* const* d_in, const int* in_sizes, int n_in,
                              void* d_out, int out_size, void* d_ws, size_t ws_size,
                              hipStream_t stream)
{
    const float* x  = (const float*)d_in[0];
    const float* W1 = (const float*)d_in[1];
    const float* U1 = (const float*)d_in[2];
    const float* b1 = (const float*)d_in[3];
    const float* W2 = (const float*)d_in[4];
    const float* U2 = (const float*)d_in[5];
    const float* b2 = (const float*)d_in[6];
    const float* Wd = (const float*)d_in[7];
    const float* bd = (const float*)d_in[8];
    float* out = (float*)d_out;
    float* ws  = (float*)d_ws;

    // h1: 2 slots x 32768 floats in d_out (128000 floats), [slot][H][B];
    // fully overwritten by dense_softmax afterwards (which reads only ws).
    float* h1b = out;

    // flag region (ints 0..1023; groups at bg*128) must start at 0
    hipMemsetAsync(ws, 0, 4096, stream);

    hipFuncSetAttribute((const void*)lstm_fused_kernel,
                        hipFuncAttributeMaxDynamicSharedMemorySize, (int)SMEM_BYTES);

    void* args[] = { (void*)&x, (void*)&W1, (void*)&U1, (void*)&b1,
                     (void*)&W2, (void*)&U2, (void*)&b2,
                     (void*)&h1b, (void*)&ws };
    hipError_t err = hipLaunchCooperativeKernel((const void*)lstm_fused_kernel,
                                                dim3(256), dim3(512), args,
                                                (int)SMEM_BYTES, stream);
    if (err != hipSuccess) {
        // R5/R6 lesson: a rejected cooperative launch fails SILENTLY without
        // this check. 256 blocks at 1/CU are co-resident by resource
        // constraints, so a plain launch preserves the flag protocol.
        hipLaunchKernelGGL(lstm_fused_kernel, dim3(256), dim3(512),
                           (int)SMEM_BYTES, stream,
                           x, W1, U1, b1, W2, U2, b2, h1b, ws);
    }

    const float* h2final = ws + 1024 + SLOT;   // slot 1 = h2[1023]
    hipLaunchKernelGGL(dense_softmax_kernel, dim3(128), dim3(256), 0, stream,
                       h2final, Wd, bd, out);
}